// Round 5
// baseline (118.862 us; speedup 1.0000x reference)
//
#include <hip/hip_runtime.h>

// Problem: B=2048, IN_DIM=1024, HID=512, FEAT=256, all fp32.
//   h_b = relu(x_b @ W_feat + b_feat); f_b = h_b @ W_br_b + b_br_b
//   out[b,c] = sum_{j,i} f1[j] f0[i] W_out[j*256+i, c] + b_out[c]
// Kron trick: W_out viewed as Wr[256,512] (Wr[j][i*2+c] = W_out[j*256+i][c]):
//   t[b,n] = sum_j f1[b,j] Wr[j,n];  out[b,c] = sum_i f0[b,i] t[b,i*2+c] + b_out[c]
// R4: t = h1@Wc + bc, Wc = W_br1@Wr (512x512), bc = b_br1@Wr.
// R8 (this round): fuse f0-GEMM + t-GEMM + kron reduction into ONE kernel.
//   Key fact: t-block at col-range [bn,bn+64) needs exactly f0 cols
//   [bn/2,bn/2+32) — a 1:1 partition, zero redundant FLOPs. Each block:
//     phase F: f-tile[64x32] = h0 @ Wb0T[bn/2..] + b_br0 -> LDS (fp32)
//     phase T: t-tile[64x64] = h1 @ WcT[bn..] (+bc folded in epilogue)
//     epilogue: p[r,c] = sum_i f[r][i] * t[r][i*2+c]; shfl-reduce; atomicAdd
//   out pre-initialized to b_out in prep. Removes kron launch, t (8MB) and
//   f0 (2MB) round-trips. Pipeline: prep -> gemm_h_wc -> gemm_ftk. 3 launches.
// History: BK=128 regressed 35us (prefetch arrays -> scratch, rule #20);
//   fp32-direct A staging regressed 3.6us (2x A-side L2 traffic). Keep BK=64,
//   named scalar prefetch regs, prep-side x->bf16.

typedef __attribute__((ext_vector_type(8))) short bf16x8;  // 8 bf16 = 4 VGPRs
typedef __attribute__((ext_vector_type(4))) float f32x4;
typedef unsigned short u16;

#define LDS_STRIDE 72   // 64 + 8 pad: row stride 144 B -> 2-way bank alias (free, m136)

__device__ __forceinline__ u16 f2bf(float f) {
    unsigned int u = __float_as_uint(f);
    return (u16)((u + 0x7FFFu + ((u >> 16) & 1u)) >> 16);   // RNE
}
__device__ __forceinline__ float bf2f(u16 h) {
    return __uint_as_float(((unsigned int)h) << 16);
}
__device__ __forceinline__ int4 cvt8(const float4& a, const float4& b) {
    int4 r;
    r.x = (int)f2bf(a.x) | ((int)f2bf(a.y) << 16);
    r.y = (int)f2bf(a.z) | ((int)f2bf(a.w) << 16);
    r.z = (int)f2bf(b.x) | ((int)f2bf(b.y) << 16);
    r.w = (int)f2bf(b.z) | ((int)f2bf(b.w) << 16);
    return r;
}

// ---------------- fused prep: all conversions in one launch ----------------
// Ranges (all block-aligned, 256 thr/blk, grid = 5202):
//  R0 [0,       262144): x0 -> bf16, 8 elems/thread
//  R1 [262144,  524288): x1 -> bf16, 8 elems/thread
//  R2 [524288, 1048576): W_feat [1024,512] -> WfT [512][1024] bf16 (transpose)
//  R3 [1048576,1179648): W_br0 [512,256] -> Wb0T [256][512] bf16 (transpose)
//  R4 [1179648,1310720): W_out (viewed Wr[256,512]) -> WrT [512][256] bf16
//  R5 [1310720,1327104): W_br1 [512,256] -> Wb1s bf16 straight copy, 8/thread
//  R6 [1327104,1327616): bc[n] = sum_j b_br1[j] * Wr[j,n]  (fp32)
//  R7 [1327616,1331712): out[idx] = b_out[idx&1]  (accumulator init)
__global__ __launch_bounds__(256) void prep(
    const float* __restrict__ x0, u16* __restrict__ xb0,
    const float* __restrict__ x1, u16* __restrict__ xb1,
    const float* __restrict__ Wf,  u16* __restrict__ WfT,
    const float* __restrict__ Wb0, u16* __restrict__ Wb0T,
    const float* __restrict__ Wout, u16* __restrict__ WrT,
    const float* __restrict__ Wb1, u16* __restrict__ Wb1s,
    const float* __restrict__ b_br1, float* __restrict__ bc,
    const float* __restrict__ b_out, float* __restrict__ out)
{
    int gid = blockIdx.x * 256 + threadIdx.x;
    if (gid < 524288) {                       // R0/R1: x conversion
        const float* s = (gid < 262144) ? x0 : x1;
        u16* d        = (gid < 262144) ? xb0 : xb1;
        int idx = (gid & 262143) * 8;
        float4 a = *(const float4*)&s[idx];
        float4 b = *(const float4*)&s[idx + 4];
        *(int4*)&d[idx] = cvt8(a, b);
    } else if (gid < 1048576) {               // R2: WfT transpose
        int local = gid - 524288;
        int k = local & 1023, n = local >> 10;
        WfT[local] = f2bf(Wf[(size_t)k * 512 + n]);
    } else if (gid < 1179648) {               // R3: Wb0T transpose
        int local = gid - 1048576;
        int k = local & 511, n = local >> 9;
        Wb0T[local] = f2bf(Wb0[(size_t)k * 256 + n]);
    } else if (gid < 1310720) {               // R4: WrT (Wr[j][n] = Wout_flat[j*512+n])
        int local = gid - 1179648;
        int j = local & 255, n = local >> 8;
        WrT[local] = f2bf(Wout[(size_t)j * 512 + n]);
    } else if (gid < 1327104) {               // R5: Wb1 straight bf16 copy
        int idx = (gid - 1310720) * 8;
        float4 a = *(const float4*)&Wb1[idx];
        float4 b = *(const float4*)&Wb1[idx + 4];
        *(int4*)&Wb1s[idx] = cvt8(a, b);
    } else if (gid < 1327616) {               // R6: bc = b_br1 @ Wr (fp32)
        int n = gid - 1327104;
        float acc = 0.0f;
        #pragma unroll 8
        for (int j = 0; j < 256; ++j)
            acc += b_br1[j] * Wout[(size_t)j * 512 + n];
        bc[n] = acc;
    } else if (gid < 1331712) {               // R7: out accumulator init
        int idx = gid - 1327616;
        out[idx] = b_out[idx & 1];
    }
}

// ---------------- shared GEMM core, BK = 64 ----------------
// C[bm..bm+64, bn..bn+64] = [relu](A @ W + bias). A: [M,K] bf16 row-major.
// WT: [N,K] bf16 (n-major). 64x64 tile, BK=64, 4 waves each 32x32
// (2x2 frags of 16x16x32). Register-prefetch pipeline with NAMED scalar
// registers (arrays here spill to scratch, rule #20; R6 measured 3x cost).
__device__ __forceinline__ void gemm_core(
    const u16* __restrict__ A, const u16* __restrict__ WT,
    const float* __restrict__ bias, void* __restrict__ Cv,
    int N, int K, int bm, int bn, int relu, int out_bf16,
    u16* As, u16* Ws)
{
    const int tid  = threadIdx.x;
    const int lane = tid & 63;
    const int wave = tid >> 6;
    const int wr   = wave >> 1;
    const int wc   = wave & 1;
    const int lrow = lane & 15;
    const int quad = lane >> 4;

    const int r0 = tid >> 3;            // rows 0..31
    const int r1 = r0 + 32;             // rows 32..63
    const int k8 = (tid & 7) * 8;

    const u16* pA0 = A  + (size_t)(bm + r0) * K + k8;
    const u16* pA1 = A  + (size_t)(bm + r1) * K + k8;
    const u16* pW0 = WT + (size_t)(bn + r0) * K + k8;
    const u16* pW1 = WT + (size_t)(bn + r1) * K + k8;

    f32x4 acc[2][2] = {};

    int4 ra0 = *(const int4*)pA0;
    int4 ra1 = *(const int4*)pA1;
    int4 rw0 = *(const int4*)pW0;
    int4 rw1 = *(const int4*)pW1;
    *(int4*)&As[r0 * LDS_STRIDE + k8] = ra0;
    *(int4*)&As[r1 * LDS_STRIDE + k8] = ra1;
    *(int4*)&Ws[r0 * LDS_STRIDE + k8] = rw0;
    *(int4*)&Ws[r1 * LDS_STRIDE + k8] = rw1;
    __syncthreads();

    for (int kk = 0; kk < K; kk += 64) {
        const int nxt = kk + 64;
        if (nxt < K) {          // prefetch next tile into registers
            ra0 = *(const int4*)(pA0 + nxt);
            ra1 = *(const int4*)(pA1 + nxt);
            rw0 = *(const int4*)(pW0 + nxt);
            rw1 = *(const int4*)(pW1 + nxt);
        }
        #pragma unroll
        for (int ks = 0; ks < 2; ++ks) {
            const int k0 = ks * 32 + quad * 8;
            bf16x8 a0 = *(const bf16x8*)&As[(wr * 32 +      lrow) * LDS_STRIDE + k0];
            bf16x8 a1 = *(const bf16x8*)&As[(wr * 32 + 16 + lrow) * LDS_STRIDE + k0];
            bf16x8 b0 = *(const bf16x8*)&Ws[(wc * 32 +      lrow) * LDS_STRIDE + k0];
            bf16x8 b1 = *(const bf16x8*)&Ws[(wc * 32 + 16 + lrow) * LDS_STRIDE + k0];
            acc[0][0] = __builtin_amdgcn_mfma_f32_16x16x32_bf16(a0, b0, acc[0][0], 0, 0, 0);
            acc[0][1] = __builtin_amdgcn_mfma_f32_16x16x32_bf16(a0, b1, acc[0][1], 0, 0, 0);
            acc[1][0] = __builtin_amdgcn_mfma_f32_16x16x32_bf16(a1, b0, acc[1][0], 0, 0, 0);
            acc[1][1] = __builtin_amdgcn_mfma_f32_16x16x32_bf16(a1, b1, acc[1][1], 0, 0, 0);
        }
        if (nxt < K) {
            __syncthreads();
            *(int4*)&As[r0 * LDS_STRIDE + k8] = ra0;
            *(int4*)&As[r1 * LDS_STRIDE + k8] = ra1;
            *(int4*)&Ws[r0 * LDS_STRIDE + k8] = rw0;
            *(int4*)&Ws[r1 * LDS_STRIDE + k8] = rw1;
            __syncthreads();
        }
    }

    // C/D layout: col=lane&15, row=quad*4+reg (verified m89/m91).
    #pragma unroll
    for (int fm = 0; fm < 2; ++fm) {
        #pragma unroll
        for (int fn = 0; fn < 2; ++fn) {
            const int c = bn + wc * 32 + fn * 16 + lrow;
            const float bv = bias ? bias[c] : 0.0f;
            #pragma unroll
            for (int reg = 0; reg < 4; ++reg) {
                const int r = bm + wr * 32 + fm * 16 + quad * 4 + reg;
                float v = acc[fm][fn][reg] + bv;
                if (relu) v = fmaxf(v, 0.0f);
                if (out_bf16) ((u16*)Cv)[(size_t)r * N + c] = f2bf(v);
                else          ((float*)Cv)[(size_t)r * N + c] = v;
            }
        }
    }
}

// Launch 2: h0/h1 = relu(x@Wf+bf) [2048x512, K=1024] + tail-merged Wc GEMM.
// grid (8, 36, 2). by<32: h-branch z. by>=32: WcT tile-row (by-32)*2+z.
// WcT[n][k] = sum_j WrT[n,j]*Wb1s[k,j] = sum_j Wr[j,n]*Wb1[k,j] = Wc[k,n].
__global__ __launch_bounds__(256) void gemm_h_wc(
    const u16* __restrict__ xb0, const u16* __restrict__ xb1,
    const u16* __restrict__ WfT, const float* __restrict__ b_feat,
    u16* __restrict__ h0, u16* __restrict__ h1,
    const u16* __restrict__ WrT, const u16* __restrict__ Wb1s,
    u16* __restrict__ WcT)
{
    __shared__ __align__(16) u16 As[64 * LDS_STRIDE];
    __shared__ __align__(16) u16 Ws[64 * LDS_STRIDE];
    const int bx = blockIdx.x, by = blockIdx.y, z = blockIdx.z;
    if (by < 32) {
        gemm_core(z ? xb1 : xb0, WfT, b_feat, z ? h1 : h0,
                  512, 1024, by * 64, bx * 64, 1, 1, As, Ws);
    } else {
        const int idx = (by - 32) * 2 + z;          // 8 tile-rows -> M=512
        gemm_core(WrT, Wb1s, nullptr, WcT,
                  512, 256, idx * 64, bx * 64, 0, 1, As, Ws);
    }
}

// Launch 3: fused f + t + kron. grid (8, 32), 256 threads.
// Block (bx, by): rows bm..bm+64, t-cols bn..bn+64, f-cols bn/2..bn/2+32.
//   phase F: fl[64][32] = h0 @ Wb0T[bn/2..] + b_br0   (fp32, in LDS)
//   phase T: acc[2][2]  = h1 @ WcT[bn..]              (bc added in epilogue)
//   epilogue: out[bm+r, n&1] += sum fl[r][n>>1 local] * (t[r][n]+bc[n])
__global__ __launch_bounds__(256) void gemm_ftk(
    const u16* __restrict__ h0, const u16* __restrict__ h1,
    const u16* __restrict__ Wb0T, const u16* __restrict__ WcT,
    const float* __restrict__ b_br0, const float* __restrict__ bc,
    float* __restrict__ out)
{
    __shared__ __align__(16) u16 As[64 * LDS_STRIDE];
    __shared__ __align__(16) u16 Ws[64 * LDS_STRIDE];
    __shared__ float fl[64][33];    // +1 pad

    const int tid  = threadIdx.x;
    const int lane = tid & 63;
    const int wave = tid >> 6;
    const int wr   = wave >> 1;
    const int wc   = wave & 1;
    const int lrow = lane & 15;
    const int quad = lane >> 4;

    const int bm = blockIdx.y * 64;
    const int bn = blockIdx.x * 64;
    const int K  = 512;

    const int r0 = tid >> 3;            // 0..31
    const int r1 = r0 + 32;
    const int k8 = (tid & 7) * 8;

    // ---------- phase F: 64x32 tile, wave w owns rows [w*16, w*16+16) ----------
    const u16* pA0 = h0   + (size_t)(bm + r0) * K + k8;
    const u16* pA1 = h0   + (size_t)(bm + r1) * K + k8;
    const u16* pWf = Wb0T + (size_t)(bn / 2 + r0) * K + k8;   // 32 rows, 1 chunk/thread

    f32x4 accf[2] = {};
    int4 ra0 = *(const int4*)pA0;
    int4 ra1 = *(const int4*)pA1;
    int4 rwf = *(const int4*)pWf;
    *(int4*)&As[r0 * LDS_STRIDE + k8] = ra0;
    *(int4*)&As[r1 * LDS_STRIDE + k8] = ra1;
    *(int4*)&Ws[r0 * LDS_STRIDE + k8] = rwf;    // rows 32..63 of Ws unused
    __syncthreads();

    for (int kk = 0; kk < K; kk += 64) {
        const int nxt = kk + 64;
        if (nxt < K) {
            ra0 = *(const int4*)(pA0 + nxt);
            ra1 = *(const int4*)(pA1 + nxt);
            rwf = *(const int4*)(pWf + nxt);
        }
        #pragma unroll
        for (int ks = 0; ks < 2; ++ks) {
            const int k0 = ks * 32 + quad * 8;
            bf16x8 a  = *(const bf16x8*)&As[(wave * 16 + lrow) * LDS_STRIDE + k0];
            bf16x8 b0 = *(const bf16x8*)&Ws[(          lrow) * LDS_STRIDE + k0];
            bf16x8 b1 = *(const bf16x8*)&Ws[(     16 + lrow) * LDS_STRIDE + k0];
            accf[0] = __builtin_amdgcn_mfma_f32_16x16x32_bf16(a, b0, accf[0], 0, 0, 0);
            accf[1] = __builtin_amdgcn_mfma_f32_16x16x32_bf16(a, b1, accf[1], 0, 0, 0);
        }
        if (nxt < K) {
            __syncthreads();
            *(int4*)&As[r0 * LDS_STRIDE + k8] = ra0;
            *(int4*)&As[r1 * LDS_STRIDE + k8] = ra1;
            *(int4*)&Ws[r0 * LDS_STRIDE + k8] = rwf;
            __syncthreads();
        }
    }
    // fl[row][col]: row = wave*16 + quad*4+reg, col = fn*16+lrow; no relu on f.
    #pragma unroll
    for (int fn = 0; fn < 2; ++fn) {
        const float bv = b_br0[bn / 2 + fn * 16 + lrow];
        #pragma unroll
        for (int reg = 0; reg < 4; ++reg)
            fl[wave * 16 + quad * 4 + reg][fn * 16 + lrow] = accf[fn][reg] + bv;
    }
    __syncthreads();    // F reads done + fl visible; As/Ws free for T

    // ---------- phase T: 64x64 tile, standard 4-wave 2x2 layout ----------
    const u16* qA0 = h1  + (size_t)(bm + r0) * K + k8;
    const u16* qA1 = h1  + (size_t)(bm + r1) * K + k8;
    const u16* qW0 = WcT + (size_t)(bn + r0) * K + k8;
    const u16* qW1 = WcT + (size_t)(bn + r1) * K + k8;

    f32x4 acc[2][2] = {};
    ra0 = *(const int4*)qA0;
    ra1 = *(const int4*)qA1;
    int4 rw0 = *(const int4*)qW0;
    int4 rw1 = *(const int4*)qW1;
    *(int4*)&As[r0 * LDS_STRIDE + k8] = ra0;
    *(int4*)&As[r1 * LDS_STRIDE + k8] = ra1;
    *(int4*)&Ws[r0 * LDS_STRIDE + k8] = rw0;
    *(int4*)&Ws[r1 * LDS_STRIDE + k8] = rw1;
    __syncthreads();

    for (int kk = 0; kk < K; kk += 64) {
        const int nxt = kk + 64;
        if (nxt < K) {
            ra0 = *(const int4*)(qA0 + nxt);
            ra1 = *(const int4*)(qA1 + nxt);
            rw0 = *(const int4*)(qW0 + nxt);
            rw1 = *(const int4*)(qW1 + nxt);
        }
        #pragma unroll
        for (int ks = 0; ks < 2; ++ks) {
            const int k0 = ks * 32 + quad * 8;
            bf16x8 a0 = *(const bf16x8*)&As[(wr * 32 +      lrow) * LDS_STRIDE + k0];
            bf16x8 a1 = *(const bf16x8*)&As[(wr * 32 + 16 + lrow) * LDS_STRIDE + k0];
            bf16x8 b0 = *(const bf16x8*)&Ws[(wc * 32 +      lrow) * LDS_STRIDE + k0];
            bf16x8 b1 = *(const bf16x8*)&Ws[(wc * 32 + 16 + lrow) * LDS_STRIDE + k0];
            acc[0][0] = __builtin_amdgcn_mfma_f32_16x16x32_bf16(a0, b0, acc[0][0], 0, 0, 0);
            acc[0][1] = __builtin_amdgcn_mfma_f32_16x16x32_bf16(a0, b1, acc[0][1], 0, 0, 0);
            acc[1][0] = __builtin_amdgcn_mfma_f32_16x16x32_bf16(a1, b0, acc[1][0], 0, 0, 0);
            acc[1][1] = __builtin_amdgcn_mfma_f32_16x16x32_bf16(a1, b1, acc[1][1], 0, 0, 0);
        }
        if (nxt < K) {
            __syncthreads();
            *(int4*)&As[r0 * LDS_STRIDE + k8] = ra0;
            *(int4*)&As[r1 * LDS_STRIDE + k8] = ra1;
            *(int4*)&Ws[r0 * LDS_STRIDE + k8] = rw0;
            *(int4*)&Ws[r1 * LDS_STRIDE + k8] = rw1;
            __syncthreads();
        }
    }

    // ---------- epilogue: kron partial + reduce + atomicAdd ----------
    // t col lc = wc*32 + fn*16 + lrow (global n = bn+lc); channel cc = lc&1 =
    // lrow&1; f index i_local = lc>>1 = wc*16 + fn*8 + (lrow>>1).
    float p[2][4];
    #pragma unroll
    for (int fm = 0; fm < 2; ++fm)
        #pragma unroll
        for (int reg = 0; reg < 4; ++reg)
            p[fm][reg] = 0.0f;

    #pragma unroll
    for (int fm = 0; fm < 2; ++fm) {
        #pragma unroll
        for (int fn = 0; fn < 2; ++fn) {
            const int   iloc = wc * 16 + fn * 8 + (lrow >> 1);
            const float bv   = bc[bn + wc * 32 + fn * 16 + lrow];
            #pragma unroll
            for (int reg = 0; reg < 4; ++reg) {
                const int r = wr * 32 + fm * 16 + quad * 4 + reg;
                p[fm][reg] += fl[r][iloc] * (acc[fm][fn][reg] + bv);
            }
        }
    }
    // reduce over lanes with same quad & same parity (xor lane bits 1..3)
    #pragma unroll
    for (int off = 2; off <= 8; off <<= 1) {
        #pragma unroll
        for (int fm = 0; fm < 2; ++fm)
            #pragma unroll
            for (int reg = 0; reg < 4; ++reg)
                p[fm][reg] += __shfl_xor(p[fm][reg], off);
    }
    if (lrow < 2) {             // lanes lrow=0 (cc=0) and lrow=1 (cc=1)
        const int cc = lrow;
        #pragma unroll
        for (int fm = 0; fm < 2; ++fm)
            #pragma unroll
            for (int reg = 0; reg < 4; ++reg) {
                const int r = bm + wr * 32 + fm * 16 + quad * 4 + reg;
                atomicAdd(&out[(size_t)r * 2 + cc], p[fm][reg]);
            }
    }
}

extern "C" void kernel_launch(void* const* d_in, const int* in_sizes, int n_in,
                              void* d_out, int out_size, void* d_ws, size_t ws_size,
                              hipStream_t stream) {
    const float* x0     = (const float*)d_in[0];
    const float* x1     = (const float*)d_in[1];
    const float* W_feat = (const float*)d_in[2];
    const float* b_feat = (const float*)d_in[3];
    const float* W_br0  = (const float*)d_in[4];
    const float* b_br0  = (const float*)d_in[5];
    const float* W_br1  = (const float*)d_in[6];
    const float* b_br1  = (const float*)d_in[7];
    const float* W_out  = (const float*)d_in[8];
    const float* b_out  = (const float*)d_in[9];
    float* out = (float*)d_out;

    const int B = 2048, IN = 1024, HID = 512, FEAT = 256;

    u16* xb0  = (u16*)d_ws;                  // [2048][1024]
    u16* xb1  = xb0  + (size_t)B * IN;       // [2048][1024]
    u16* WfT  = xb1  + (size_t)B * IN;       // [512][1024]
    u16* Wb0T = WfT  + (size_t)HID * IN;     // [256][512]
    u16* WrT  = Wb0T + (size_t)FEAT * HID;   // [512][256]
    u16* Wb1s = WrT  + (size_t)HID * FEAT;   // [512][256] straight copy
    u16* WcT  = Wb1s + (size_t)HID * FEAT;   // [512][512]
    u16* h0   = WcT  + (size_t)HID * HID;    // [2048][512] bf16
    u16* h1   = h0   + (size_t)B * HID;
    float* bc = (float*)(h1 + (size_t)B * HID);    // [512] fp32
    // total ~14.5 MiB of d_ws

    dim3 blk(256);

    // 1. all conversions + bc + out-init in one launch (ranges block-aligned)
    prep<<<dim3(5202), blk, 0, stream>>>(
        x0, xb0, x1, xb1, W_feat, WfT, W_br0, Wb0T, W_out, WrT,
        W_br1, Wb1s, b_br1, bc, b_out, out);

    // 2. h0,h1 (K=1024) + Wc = W_br1@Wr (K=256) tail-merged
    gemm_h_wc<<<dim3(8, 36, 2), blk, 0, stream>>>(
        xb0, xb1, WfT, b_feat, h0, h1, WrT, Wb1s, WcT);

    // 3. fused f + t + kron -> atomicAdd into out (pre-inited to b_out)
    gemm_ftk<<<dim3(8, 32), blk, 0, stream>>>(
        h0, h1, Wb0T, WcT, b_br0, bc, out);
}

// Round 6
// 118.720 us; speedup vs baseline: 1.0012x; 1.0012x over previous
//
#include <hip/hip_runtime.h>

// Problem: B=2048, IN_DIM=1024, HID=512, FEAT=256, all fp32.
//   h_b = relu(x_b @ W_feat + b_feat); f_b = h_b @ W_br_b + b_br_b
//   out[b,c] = sum_{j,i} f1[j] f0[i] W_out[j*256+i, c] + b_out[c]
// Kron trick: W_out viewed as Wr[256,512] (Wr[j][i*2+c] = W_out[j*256+i][c]):
//   t[b,n] = sum_j f1[b,j] Wr[j,n];  out[b,c] = sum_i f0[b,i] t[b,i*2+c] + b_out[c]
// Structural fusion: t = h1@Wc + bc, Wc = W_br1@Wr (512x512), bc = b_br1@Wr.
// R9 (this round): VERBATIM REVERT to R7 — the measured champion (115.9us).
//   R8's ftk-fusion regressed +3.0us: it serialized the f-GEMM and t-GEMM
//   phases inside 256 blocks (1 block/CU, no overlap) where R7 ran them as
//   384 concurrent blocks; traffic savings < concurrency loss.
// Experiment ledger (dur_us): R0 119.4 | R4 120.9 | R5 fp32-staging 124.5 |
//   R6 BK=128 159.6 (scratch spill, rule #20) | R7 115.9 | R8 ftk-fuse 118.9.
//   ~90us of every measurement is the harness's 2x268MB workspace-poison
//   fills (the only top-5 dispatches in all rounds, invariant to our code).
// Pipeline: prep -> gemm_h_wc (h + tail-merged Wc) -> gemm_ft (f0||t) -> kron.

typedef __attribute__((ext_vector_type(8))) short bf16x8;  // 8 bf16 = 4 VGPRs
typedef __attribute__((ext_vector_type(4))) float f32x4;
typedef unsigned short u16;

#define LDS_STRIDE 72   // 64 + 8 pad: row stride 144 B -> 2-way bank alias (free, m136)

__device__ __forceinline__ u16 f2bf(float f) {
    unsigned int u = __float_as_uint(f);
    return (u16)((u + 0x7FFFu + ((u >> 16) & 1u)) >> 16);   // RNE
}
__device__ __forceinline__ float bf2f(u16 h) {
    return __uint_as_float(((unsigned int)h) << 16);
}
__device__ __forceinline__ int4 cvt8(const float4& a, const float4& b) {
    int4 r;
    r.x = (int)f2bf(a.x) | ((int)f2bf(a.y) << 16);
    r.y = (int)f2bf(a.z) | ((int)f2bf(a.w) << 16);
    r.z = (int)f2bf(b.x) | ((int)f2bf(b.y) << 16);
    r.w = (int)f2bf(b.z) | ((int)f2bf(b.w) << 16);
    return r;
}

// ---------------- fused prep: all conversions in one launch ----------------
// Ranges (all block-aligned, 256 thr/blk, grid = 5186):
//  R0 [0,       262144): x0 -> bf16, 8 elems/thread
//  R1 [262144,  524288): x1 -> bf16, 8 elems/thread
//  R2 [524288, 1048576): W_feat [1024,512] -> WfT [512][1024] bf16 (transpose)
//  R3 [1048576,1179648): W_br0 [512,256] -> Wb0T [256][512] bf16 (transpose)
//  R4 [1179648,1310720): W_out (viewed Wr[256,512]) -> WrT [512][256] bf16
//  R5 [1310720,1327104): W_br1 [512,256] -> Wb1s bf16 straight copy, 8/thread
//  R6 [1327104,1327616): bc[n] = sum_j b_br1[j] * Wr[j,n]  (fp32)
__global__ __launch_bounds__(256) void prep(
    const float* __restrict__ x0, u16* __restrict__ xb0,
    const float* __restrict__ x1, u16* __restrict__ xb1,
    const float* __restrict__ Wf,  u16* __restrict__ WfT,
    const float* __restrict__ Wb0, u16* __restrict__ Wb0T,
    const float* __restrict__ Wout, u16* __restrict__ WrT,
    const float* __restrict__ Wb1, u16* __restrict__ Wb1s,
    const float* __restrict__ b_br1, float* __restrict__ bc)
{
    int gid = blockIdx.x * 256 + threadIdx.x;
    if (gid < 524288) {                       // R0/R1: x conversion
        const float* s = (gid < 262144) ? x0 : x1;
        u16* d        = (gid < 262144) ? xb0 : xb1;
        int idx = (gid & 262143) * 8;
        float4 a = *(const float4*)&s[idx];
        float4 b = *(const float4*)&s[idx + 4];
        *(int4*)&d[idx] = cvt8(a, b);
    } else if (gid < 1048576) {               // R2: WfT transpose
        int local = gid - 524288;
        int k = local & 1023, n = local >> 10;
        WfT[local] = f2bf(Wf[(size_t)k * 512 + n]);
    } else if (gid < 1179648) {               // R3: Wb0T transpose
        int local = gid - 1048576;
        int k = local & 511, n = local >> 9;
        Wb0T[local] = f2bf(Wb0[(size_t)k * 256 + n]);
    } else if (gid < 1310720) {               // R4: WrT (Wr[j][n] = Wout_flat[j*512+n])
        int local = gid - 1179648;
        int j = local & 255, n = local >> 8;
        WrT[local] = f2bf(Wout[(size_t)j * 512 + n]);
    } else if (gid < 1327104) {               // R5: Wb1 straight bf16 copy
        int idx = (gid - 1310720) * 8;
        float4 a = *(const float4*)&Wb1[idx];
        float4 b = *(const float4*)&Wb1[idx + 4];
        *(int4*)&Wb1s[idx] = cvt8(a, b);
    } else if (gid < 1327616) {               // R6: bc = b_br1 @ Wr (fp32)
        int n = gid - 1327104;
        float acc = 0.0f;
        #pragma unroll 8
        for (int j = 0; j < 256; ++j)
            acc += b_br1[j] * Wout[(size_t)j * 512 + n];
        bc[n] = acc;
    }
}

// ---------------- shared GEMM core, BK = 64 ----------------
// C[bm..bm+64, bn..bn+64] = [relu](A @ W + bias). A: [M,K] bf16 row-major.
// WT: [N,K] bf16 (n-major). 64x64 tile, BK=64, 4 waves each 32x32
// (2x2 frags of 16x16x32). Register-prefetch pipeline with NAMED scalar
// registers (int4 ra0/ra1/rw0/rw1 — arrays here spill to scratch, rule #20;
// R6 measured that at 3x cost). Issue tile k+1 loads before computing tile k.
__device__ __forceinline__ void gemm_core(
    const u16* __restrict__ A, const u16* __restrict__ WT,
    const float* __restrict__ bias, void* __restrict__ Cv,
    int N, int K, int bm, int bn, int relu, int out_bf16,
    u16* As, u16* Ws)
{
    const int tid  = threadIdx.x;
    const int lane = tid & 63;
    const int wave = tid >> 6;
    const int wr   = wave >> 1;
    const int wc   = wave & 1;
    const int lrow = lane & 15;
    const int quad = lane >> 4;

    // staging: 512 chunks of 8 bf16 per tile; thread covers rows r0 and r1
    const int r0 = tid >> 3;            // rows 0..31
    const int r1 = r0 + 32;             // rows 32..63
    const int k8 = (tid & 7) * 8;

    const u16* pA0 = A  + (size_t)(bm + r0) * K + k8;
    const u16* pA1 = A  + (size_t)(bm + r1) * K + k8;
    const u16* pW0 = WT + (size_t)(bn + r0) * K + k8;
    const u16* pW1 = WT + (size_t)(bn + r1) * K + k8;

    f32x4 acc[2][2] = {};

    int4 ra0 = *(const int4*)pA0;
    int4 ra1 = *(const int4*)pA1;
    int4 rw0 = *(const int4*)pW0;
    int4 rw1 = *(const int4*)pW1;
    *(int4*)&As[r0 * LDS_STRIDE + k8] = ra0;
    *(int4*)&As[r1 * LDS_STRIDE + k8] = ra1;
    *(int4*)&Ws[r0 * LDS_STRIDE + k8] = rw0;
    *(int4*)&Ws[r1 * LDS_STRIDE + k8] = rw1;
    __syncthreads();

    for (int kk = 0; kk < K; kk += 64) {
        const int nxt = kk + 64;
        if (nxt < K) {          // prefetch next tile into registers
            ra0 = *(const int4*)(pA0 + nxt);
            ra1 = *(const int4*)(pA1 + nxt);
            rw0 = *(const int4*)(pW0 + nxt);
            rw1 = *(const int4*)(pW1 + nxt);
        }
        #pragma unroll
        for (int ks = 0; ks < 2; ++ks) {
            const int k0 = ks * 32 + quad * 8;
            bf16x8 a0 = *(const bf16x8*)&As[(wr * 32 +      lrow) * LDS_STRIDE + k0];
            bf16x8 a1 = *(const bf16x8*)&As[(wr * 32 + 16 + lrow) * LDS_STRIDE + k0];
            bf16x8 b0 = *(const bf16x8*)&Ws[(wc * 32 +      lrow) * LDS_STRIDE + k0];
            bf16x8 b1 = *(const bf16x8*)&Ws[(wc * 32 + 16 + lrow) * LDS_STRIDE + k0];
            acc[0][0] = __builtin_amdgcn_mfma_f32_16x16x32_bf16(a0, b0, acc[0][0], 0, 0, 0);
            acc[0][1] = __builtin_amdgcn_mfma_f32_16x16x32_bf16(a0, b1, acc[0][1], 0, 0, 0);
            acc[1][0] = __builtin_amdgcn_mfma_f32_16x16x32_bf16(a1, b0, acc[1][0], 0, 0, 0);
            acc[1][1] = __builtin_amdgcn_mfma_f32_16x16x32_bf16(a1, b1, acc[1][1], 0, 0, 0);
        }
        if (nxt < K) {
            __syncthreads();
            *(int4*)&As[r0 * LDS_STRIDE + k8] = ra0;
            *(int4*)&As[r1 * LDS_STRIDE + k8] = ra1;
            *(int4*)&Ws[r0 * LDS_STRIDE + k8] = rw0;
            *(int4*)&Ws[r1 * LDS_STRIDE + k8] = rw1;
            __syncthreads();
        }
    }

    // C/D layout: col=lane&15, row=quad*4+reg (verified m89/m91).
    #pragma unroll
    for (int fm = 0; fm < 2; ++fm) {
        #pragma unroll
        for (int fn = 0; fn < 2; ++fn) {
            const int c = bn + wc * 32 + fn * 16 + lrow;
            const float bv = bias ? bias[c] : 0.0f;
            #pragma unroll
            for (int reg = 0; reg < 4; ++reg) {
                const int r = bm + wr * 32 + fm * 16 + quad * 4 + reg;
                float v = acc[fm][fn][reg] + bv;
                if (relu) v = fmaxf(v, 0.0f);
                if (out_bf16) ((u16*)Cv)[(size_t)r * N + c] = f2bf(v);
                else          ((float*)Cv)[(size_t)r * N + c] = v;
            }
        }
    }
}

// Launch 2: h0/h1 = relu(x@Wf+bf) [2048x512, K=1024] + tail-merged Wc GEMM.
// grid (8, 36, 2). by<32: h-branch z. by>=32: WcT tile-row (by-32)*2+z.
// WcT[n][k] = sum_j WrT[n,j]*Wb1s[k,j] = sum_j Wr[j,n]*Wb1[k,j] = Wc[k,n].
__global__ __launch_bounds__(256) void gemm_h_wc(
    const u16* __restrict__ xb0, const u16* __restrict__ xb1,
    const u16* __restrict__ WfT, const float* __restrict__ b_feat,
    u16* __restrict__ h0, u16* __restrict__ h1,
    const u16* __restrict__ WrT, const u16* __restrict__ Wb1s,
    u16* __restrict__ WcT)
{
    __shared__ __align__(16) u16 As[64 * LDS_STRIDE];
    __shared__ __align__(16) u16 Ws[64 * LDS_STRIDE];
    const int bx = blockIdx.x, by = blockIdx.y, z = blockIdx.z;
    if (by < 32) {
        gemm_core(z ? xb1 : xb0, WfT, b_feat, z ? h1 : h0,
                  512, 1024, by * 64, bx * 64, 1, 1, As, Ws);
    } else {
        const int idx = (by - 32) * 2 + z;          // 8 tile-rows -> M=512
        gemm_core(WrT, Wb1s, nullptr, WcT,
                  512, 256, idx * 64, bx * 64, 0, 1, As, Ws);
    }
}

// Launch 3, flat grid (12, 32): bx<4: f0 = h0@Wb0 + b_br0 [2048x256] bf16
//                               bx>=4: t  = h1@Wc  + bc    [2048x512] fp32
__global__ __launch_bounds__(256) void gemm_ft(
    const u16* __restrict__ h0, const u16* __restrict__ h1,
    const u16* __restrict__ Wb0T, const u16* __restrict__ WcT,
    const float* __restrict__ b_br0, const float* __restrict__ bc,
    u16* __restrict__ f0, float* __restrict__ t)
{
    __shared__ __align__(16) u16 As[64 * LDS_STRIDE];
    __shared__ __align__(16) u16 Ws[64 * LDS_STRIDE];
    const int bx = blockIdx.x;
    if (bx < 4) {
        gemm_core(h0, Wb0T, b_br0, f0,
                  256, 512, blockIdx.y * 64, bx * 64, 0, 1, As, Ws);
    } else {
        gemm_core(h1, WcT, bc, t,
                  512, 512, blockIdx.y * 64, (bx - 4) * 64, 0, 0, As, Ws);
    }
}

// out[b,c] = sum_i f0[b,i] * t[b, i*2+c] + b_out[c].
// One WAVE per row b; 4 rows per 256-thread block; grid = 512.
__global__ __launch_bounds__(256) void kron_reduce(
    const u16* __restrict__ f0, const float* __restrict__ t,
    const float* __restrict__ b_out, float* __restrict__ out)
{
    const int wave = threadIdx.x >> 6;
    const int lane = threadIdx.x & 63;
    const int b = blockIdx.x * 4 + wave;

    const u16*   fr = f0 + (size_t)b * 256;
    const float* tr = t  + (size_t)b * 512;

    float p0 = 0.0f, p1 = 0.0f;
    #pragma unroll
    for (int q = 0; q < 4; ++q) {
        const int i = lane + 64 * q;
        const float  v  = bf2f(fr[i]);
        const float2 tv = ((const float2*)tr)[i];
        p0 += v * tv.x;
        p1 += v * tv.y;
    }
    #pragma unroll
    for (int off = 32; off > 0; off >>= 1) {
        p0 += __shfl_down(p0, off);
        p1 += __shfl_down(p1, off);
    }
    if (lane == 0) {
        float2 o;
        o.x = p0 + b_out[0];
        o.y = p1 + b_out[1];
        ((float2*)out)[b] = o;
    }
}

extern "C" void kernel_launch(void* const* d_in, const int* in_sizes, int n_in,
                              void* d_out, int out_size, void* d_ws, size_t ws_size,
                              hipStream_t stream) {
    const float* x0     = (const float*)d_in[0];
    const float* x1     = (const float*)d_in[1];
    const float* W_feat = (const float*)d_in[2];
    const float* b_feat = (const float*)d_in[3];
    const float* W_br0  = (const float*)d_in[4];
    const float* b_br0  = (const float*)d_in[5];
    const float* W_br1  = (const float*)d_in[6];
    const float* b_br1  = (const float*)d_in[7];
    const float* W_out  = (const float*)d_in[8];
    const float* b_out  = (const float*)d_in[9];
    float* out = (float*)d_out;

    const int B = 2048, IN = 1024, HID = 512, FEAT = 256;

    u16* xb0  = (u16*)d_ws;                  // [2048][1024]
    u16* xb1  = xb0  + (size_t)B * IN;       // [2048][1024]
    u16* WfT  = xb1  + (size_t)B * IN;       // [512][1024]
    u16* Wb0T = WfT  + (size_t)HID * IN;     // [256][512]
    u16* WrT  = Wb0T + (size_t)FEAT * HID;   // [512][256]
    u16* Wb1s = WrT  + (size_t)HID * FEAT;   // [512][256] straight copy
    u16* WcT  = Wb1s + (size_t)HID * FEAT;   // [512][512]
    u16* h0   = WcT  + (size_t)HID * HID;    // [2048][512] bf16
    u16* h1   = h0   + (size_t)B * HID;
    u16* f0   = h1   + (size_t)B * HID;      // [2048][256] bf16
    float* t  = (float*)(f0 + (size_t)B * FEAT);   // [2048][512] fp32
    float* bc = t + (size_t)B * HID;         // [512] fp32
    // total ~19.5 MiB of d_ws

    dim3 blk(256);

    // 1. all conversions + bc in one launch (ranges block-aligned)
    prep<<<dim3(5186), blk, 0, stream>>>(
        x0, xb0, x1, xb1, W_feat, WfT, W_br0, Wb0T, W_out, WrT,
        W_br1, Wb1s, b_br1, bc);

    // 2. h0,h1 (K=1024) + Wc = W_br1@Wr (K=256) tail-merged
    gemm_h_wc<<<dim3(8, 36, 2), blk, 0, stream>>>(
        xb0, xb1, WfT, b_feat, h0, h1, WrT, Wb1s, WcT);

    // 3. f0 = h0@Wb0+b_br0 (bf16) || t = h1@Wc+bc (fp32), flat grid
    gemm_ft<<<dim3(12, 32), blk, 0, stream>>>(
        h0, h1, Wb0T, WcT, b_br0, bc, f0, t);

    // 4. out[b,c] = sum_i f0[b,i]*t[b,i*2+c] + b_out[c]; wave-per-row
    kron_reduce<<<dim3(512), blk, 0, stream>>>(f0, t, b_out, out);
}